// Round 2
// baseline (1645.283 us; speedup 1.0000x reference)
//
#include <hip/hip_runtime.h>
#include <hip/hip_bf16.h>

// GRU: B=256, T=2048, I=10, H=64. PyTorch gate order (r, z, n).
// One block per batch element (256 blocks, 1/CU). 192 threads = 3 waves:
// wave g handles gate g for all 64 hidden units; thread owns its W_hh row
// in VGPRs. h broadcast via LDS; internal math fp32.
//
// Dtype is resolved AT RUNTIME (device-side): a probe kernel inspects w_ih
// bit patterns and writes a flag into d_ws; fp32 and bf16 template variants
// both launch and the non-matching one exits immediately.

#define Bn 256
#define Tn 2048
#define In 10
#define Hn 64

typedef __hip_bfloat16 bf16;

__device__ __forceinline__ float ldf(const float* p) { return *p; }
__device__ __forceinline__ float ldf(const bf16* p)  { return __bfloat162float(*p); }
__device__ __forceinline__ void stf(float* p, float v) { *p = v; }
__device__ __forceinline__ void stf(bf16* p, float v)  { *p = __float2bfloat16(v); }

// Probe: w_ih ~ uniform(-0.125, 0.125).
// If buffer is bf16: low 16 bits of each 32-bit word are a bf16 value in
// that range -> exponent field (bits 14..7) in [0x6C, 0x7C] w.p. ~1.
// If buffer is fp32: low 16 bits are uniform mantissa bits -> ~6.6% hit rate.
__global__ void detect_dtype(const unsigned int* __restrict__ w,
                             int* __restrict__ flag) {
    if (threadIdx.x == 0 && blockIdx.x == 0) {
        int hits = 0;
        for (int i = 0; i < 64; ++i) {
            unsigned int e = (w[i] >> 7) & 0xFF;  // exponent field of low half
            if (e >= 0x6C && e <= 0x7C) hits++;
        }
        *flag = (hits >= 32) ? 1 : 0;  // 1 = bf16 data, 0 = fp32 data
    }
}

template <typename T>
__global__ __launch_bounds__(192, 1) void gru_kernel(
    const T* __restrict__ noise,  // (B, T, I)
    const T* __restrict__ w_ih,   // (3H, I)
    const T* __restrict__ w_hh,   // (3H, H)
    const T* __restrict__ b_ih,   // (3H)
    const T* __restrict__ b_hh,   // (3H)
    T* __restrict__ out,          // (B, T, H)
    const int* __restrict__ flag, int my_tag)
{
    if (*flag != my_tag) return;  // uniform early-exit (before any barrier)

    const int b = blockIdx.x;
    const int tid = threadIdx.x;      // [0, 192)
    const int gate = tid >> 6;        // 0=r, 1=z, 2=n
    const int j = tid & 63;           // hidden unit

    __shared__ __align__(16) float h_s[Hn];
    __shared__ __align__(16) float r_s[Hn];
    __shared__ __align__(16) float z_s[Hn];

    // One-time weight load into registers (fp32).
    float wr[Hn];
#pragma unroll
    for (int k = 0; k < Hn; ++k) wr[k] = ldf(&w_hh[tid * Hn + k]);
    float wi[In];
#pragma unroll
    for (int i = 0; i < In; ++i) wi[i] = ldf(&w_ih[tid * In + i]);
    const float bi = ldf(&b_ih[tid]);
    const float bh = ldf(&b_hh[tid]);

    if (tid < Hn) h_s[tid] = 0.0f;
    __syncthreads();

    const T* __restrict__ xp = noise + (size_t)b * Tn * In;
    T* __restrict__ op = out + (size_t)b * Tn * Hn;

    // Prefetch x for t=0 (same 10 values for all threads; L1 broadcast).
    float xc[In];
#pragma unroll
    for (int i = 0; i < In; ++i) xc[i] = ldf(&xp[i]);

    for (int t = 0; t < Tn; ++t) {
        // gi = x_t . w_ih_row + b_ih  (independent of h)
        float gi = bi;
#pragma unroll
        for (int i = 0; i < In; ++i) gi += wi[i] * xc[i];

        // Prefetch next timestep's x.
        float xn[In];
        if (t + 1 < Tn) {
            const T* xq = xp + (size_t)(t + 1) * In;
#pragma unroll
            for (int i = 0; i < In; ++i) xn[i] = ldf(&xq[i]);
        } else {
#pragma unroll
            for (int i = 0; i < In; ++i) xn[i] = 0.0f;
        }

        // a = W_row . h  — 16x ds_read_b128 broadcast + 64 FMAs, 4 chains.
        const float4* h4 = (const float4*)h_s;
        float a0 = 0.f, a1 = 0.f, a2 = 0.f, a3 = 0.f;
#pragma unroll
        for (int k = 0; k < Hn / 4; ++k) {
            float4 hv = h4[k];
            a0 += wr[4 * k + 0] * hv.x;
            a1 += wr[4 * k + 1] * hv.y;
            a2 += wr[4 * k + 2] * hv.z;
            a3 += wr[4 * k + 3] * hv.w;
        }
        const float a = (a0 + a1) + (a2 + a3);
        const float hold = h_s[j];  // old h_j (for the z*h term)

        if (gate < 2) {
            // r or z: sigmoid(gi + a + b_hh)
            const float pre = gi + a + bh;
            const float v = 1.0f / (1.0f + __expf(-pre));
            if (gate == 0) r_s[j] = v;
            else           z_s[j] = v;
        }
        __syncthreads();  // r_s/z_s ready for the n-wave

        if (gate == 2) {
            const float r = r_s[j];
            const float z = z_s[j];
            const float pre = gi + r * (a + bh);
            // tanh(x) = 1 - 2/(exp(2x)+1); saturates correctly at +/-1.
            const float e = __expf(2.0f * pre);
            const float n = 1.0f - 2.0f / (e + 1.0f);
            const float hn = (1.0f - z) * n + z * hold;
            h_s[j] = hn;
            stf(&op[(size_t)t * Hn + j], hn);
        }
        __syncthreads();  // h_s(t+1) visible to all waves

#pragma unroll
        for (int i = 0; i < In; ++i) xc[i] = xn[i];
    }
}

extern "C" void kernel_launch(void* const* d_in, const int* in_sizes, int n_in,
                              void* d_out, int out_size, void* d_ws, size_t ws_size,
                              hipStream_t stream) {
    int* flag = (int*)d_ws;

    detect_dtype<<<1, 64, 0, stream>>>((const unsigned int*)d_in[1], flag);

    // fp32 variant (tag 0)
    gru_kernel<float><<<Bn, 192, 0, stream>>>(
        (const float*)d_in[0], (const float*)d_in[1], (const float*)d_in[2],
        (const float*)d_in[3], (const float*)d_in[4], (float*)d_out, flag, 0);

    // bf16 variant (tag 1)
    gru_kernel<bf16><<<Bn, 192, 0, stream>>>(
        (const bf16*)d_in[0], (const bf16*)d_in[1], (const bf16*)d_in[2],
        (const bf16*)d_in[3], (const bf16*)d_in[4], (bf16*)d_out, flag, 1);
}

// Round 3
// 1465.187 us; speedup vs baseline: 1.1229x; 1.1229x over previous
//
#include <hip/hip_runtime.h>

// GRU: B=256, T=2048, I=10, H=64, fp32 in/out (confirmed: WRITE_SIZE=134MB fp32).
// One block = one batch = ONE wave (64 lanes). Lane j owns hidden unit j and
// computes all three gates (r,z,n): 3 rows of W_hh live in VGPRs (~280 regs,
// OK under gfx950's unified 512-reg budget at 1 wave/SIMD). h broadcast via
// 16x ds_read_b128; single-wave barrier is ~free; no cross-wave r/z exchange.
// Matvec written in float2 ext-vectors so the compiler emits v_pk_fma_f32.

#define Bn 256
#define Tn 2048
#define In 10
#define Hn 64

typedef float v2f __attribute__((ext_vector_type(2)));

__global__ __launch_bounds__(64, 1) void gru_kernel(
    const float* __restrict__ noise,  // (B, T, I)
    const float* __restrict__ w_ih,   // (3H, I)
    const float* __restrict__ w_hh,   // (3H, H)
    const float* __restrict__ b_ih,   // (3H)
    const float* __restrict__ b_hh,   // (3H)
    float* __restrict__ out)          // (B, T, H)
{
    const int b = blockIdx.x;
    const int j = threadIdx.x;  // hidden unit, 0..63

    __shared__ __align__(16) float h_s[Hn];

    // --- one-time: load this lane's 3 W_hh rows (r,z,n) into registers ---
    v2f wr_r[Hn / 2], wr_z[Hn / 2], wr_n[Hn / 2];
    {
        const float* pr = w_hh + (size_t)(0 * Hn + j) * Hn;
        const float* pz = w_hh + (size_t)(1 * Hn + j) * Hn;
        const float* pn = w_hh + (size_t)(2 * Hn + j) * Hn;
#pragma unroll
        for (int k = 0; k < Hn / 2; ++k) {
            wr_r[k] = v2f{pr[2 * k], pr[2 * k + 1]};
            wr_z[k] = v2f{pz[2 * k], pz[2 * k + 1]};
            wr_n[k] = v2f{pn[2 * k], pn[2 * k + 1]};
        }
    }
    float wi_r[In], wi_z[In], wi_n[In];
#pragma unroll
    for (int i = 0; i < In; ++i) {
        wi_r[i] = w_ih[(0 * Hn + j) * In + i];
        wi_z[i] = w_ih[(1 * Hn + j) * In + i];
        wi_n[i] = w_ih[(2 * Hn + j) * In + i];
    }
    // biases: r/z fold (b_ih + b_hh); n keeps b_hh separate (inside r*(...)).
    const float brs = b_ih[0 * Hn + j] + b_hh[0 * Hn + j];
    const float bzs = b_ih[1 * Hn + j] + b_hh[1 * Hn + j];
    const float bin = b_ih[2 * Hn + j];
    const float bhn = b_hh[2 * Hn + j];

    h_s[j] = 0.0f;
    float hold = 0.0f;  // this lane's h_j, carried in a register
    __syncthreads();

    const float* __restrict__ xp = noise + (size_t)b * Tn * In;
    float* __restrict__ op = out + (size_t)b * Tn * Hn;

    // x_t is wave-uniform (same 10 floats for all lanes) -> scalar loads.
    float xc[In];
#pragma unroll
    for (int i = 0; i < In; ++i) xc[i] = xp[i];

    for (int t = 0; t < Tn; ++t) {
        // gi for all three gates (input projection, independent of h).
        float gr = brs, gz = bzs, gn = bin;
#pragma unroll
        for (int i = 0; i < In; ++i) {
            gr += wi_r[i] * xc[i];
            gz += wi_z[i] * xc[i];
            gn += wi_n[i] * xc[i];
        }

        // Prefetch next x (uniform -> s_load; latency hidden under matvec).
        float xn_[In];
        if (t + 1 < Tn) {
            const float* xq = xp + (size_t)(t + 1) * In;
#pragma unroll
            for (int i = 0; i < In; ++i) xn_[i] = xq[i];
        } else {
#pragma unroll
            for (int i = 0; i < In; ++i) xn_[i] = 0.0f;
        }

        // Matvec: a_g = W_g[j,:] . h for g in {r,z,n}.
        // 16x ds_read_b128 (broadcast, conflict-free) + packed fp32 FMAs.
        const float4* h4 = (const float4*)h_s;
        v2f ar0 = {0.f, 0.f}, ar1 = {0.f, 0.f};
        v2f az0 = {0.f, 0.f}, az1 = {0.f, 0.f};
        v2f an0 = {0.f, 0.f}, an1 = {0.f, 0.f};
#pragma unroll
        for (int kk = 0; kk < Hn / 4; ++kk) {
            float4 hv = h4[kk];
            v2f h0 = {hv.x, hv.y};
            v2f h1 = {hv.z, hv.w};
            ar0 += wr_r[2 * kk] * h0;
            ar1 += wr_r[2 * kk + 1] * h1;
            az0 += wr_z[2 * kk] * h0;
            az1 += wr_z[2 * kk + 1] * h1;
            an0 += wr_n[2 * kk] * h0;
            an1 += wr_n[2 * kk + 1] * h1;
        }
        v2f arv = ar0 + ar1, azv = az0 + az1, anv = an0 + an1;
        const float ar = arv.x + arv.y;
        const float az = azv.x + azv.y;
        const float an = anv.x + anv.y;

        // Gates (fp32). tanh via exp(2x) form — saturates correctly.
        const float r = 1.0f / (1.0f + __expf(-(gr + ar)));
        const float z = 1.0f / (1.0f + __expf(-(gz + az)));
        const float pre_n = gn + r * (an + bhn);
        const float e = __expf(2.0f * pre_n);
        const float nn = 1.0f - 2.0f / (e + 1.0f);
        const float hn = z * (hold - nn) + nn;  // == (1-z)*n + z*h

        op[(size_t)t * Hn + j] = hn;

        // Publish h for next step. Single wave: reads above (program order)
        // hit the LDS pipe before this write; barrier is cheap (1 wave).
        h_s[j] = hn;
        hold = hn;
        __syncthreads();

#pragma unroll
        for (int i = 0; i < In; ++i) xc[i] = xn_[i];
    }
}

extern "C" void kernel_launch(void* const* d_in, const int* in_sizes, int n_in,
                              void* d_out, int out_size, void* d_ws, size_t ws_size,
                              hipStream_t stream) {
    gru_kernel<<<Bn, 64, 0, stream>>>(
        (const float*)d_in[0], (const float*)d_in[1], (const float*)d_in[2],
        (const float*)d_in[3], (const float*)d_in[4], (float*)d_out);
}

// Round 4
// 1244.999 us; speedup vs baseline: 1.3215x; 1.1769x over previous
//
#include <hip/hip_runtime.h>

// GRU: B=256, T=2048, I=10, H=64, fp32 in/out.
// One block = one batch = ONE wave. Lane j owns hidden unit j, all 3 gates.
// Round-3 failure: 3 gates x 64 fp32 weights/lane = >256 arch VGPRs -> scratch
// spill (VGPR_Count=128 + scratch reloads dominated). Fix: weights packed f16
// (96 VGPRs) + v_dot2_f32_f16 (2 MACs/instr, fp32 accumulate). h broadcast via
// LDS as packed f16 (8x ds_read_b128); single wave -> in-order LDS pipe, no
// barriers at all.

#define Bn 256
#define Tn 2048
#define In 10
#define Hn 64

typedef _Float16 h2 __attribute__((ext_vector_type(2)));

__device__ __forceinline__ float dot2(h2 a, h2 b, float c) {
    return __builtin_amdgcn_fdot2(a, b, c, false);
}

__global__ __launch_bounds__(64, 1) void gru_kernel(
    const float* __restrict__ noise,  // (B, T, I)
    const float* __restrict__ w_ih,   // (3H, I)
    const float* __restrict__ w_hh,   // (3H, H)
    const float* __restrict__ b_ih,   // (3H)
    const float* __restrict__ b_hh,   // (3H)
    float* __restrict__ out)          // (B, T, H)
{
    const int b = blockIdx.x;
    const int j = threadIdx.x;  // hidden unit 0..63

    __shared__ alignas(16) unsigned short hbuf[Hn];  // h as f16 bits

    // --- one-time: this lane's 3 W_hh rows, packed f16 (96 VGPRs total) ---
    h2 wr[Hn / 2], wz[Hn / 2], wn[Hn / 2];
    {
        const float* pr = w_hh + (size_t)(0 * Hn + j) * Hn;
        const float* pz = w_hh + (size_t)(1 * Hn + j) * Hn;
        const float* pn = w_hh + (size_t)(2 * Hn + j) * Hn;
#pragma unroll
        for (int k = 0; k < Hn / 2; ++k) {
            wr[k] = h2{(_Float16)pr[2 * k], (_Float16)pr[2 * k + 1]};
            wz[k] = h2{(_Float16)pz[2 * k], (_Float16)pz[2 * k + 1]};
            wn[k] = h2{(_Float16)pn[2 * k], (_Float16)pn[2 * k + 1]};
        }
    }
    // w_ih rows in fp32 (x-projection stays fp32; 30 VGPRs).
    float wir[In], wiz[In], win[In];
#pragma unroll
    for (int i = 0; i < In; ++i) {
        wir[i] = w_ih[(0 * Hn + j) * In + i];
        wiz[i] = w_ih[(1 * Hn + j) * In + i];
        win[i] = w_ih[(2 * Hn + j) * In + i];
    }
    const float brz_r = b_ih[0 * Hn + j] + b_hh[0 * Hn + j];
    const float brz_z = b_ih[1 * Hn + j] + b_hh[1 * Hn + j];
    const float bi_n  = b_ih[2 * Hn + j];
    const float bh_n  = b_hh[2 * Hn + j];

    hbuf[j] = 0;       // f16 +0.0
    float hold = 0.0f; // lane's own h_j in fp32 (recurrent blend stays fp32)

    const float* __restrict__ xp = noise + (size_t)b * Tn * In;
    float* __restrict__ op = out + (size_t)b * Tn * Hn;

    // x_t is wave-uniform -> scalar loads; prefetched one step ahead.
    float xc[In];
#pragma unroll
    for (int i = 0; i < In; ++i) xc[i] = xp[i];

    for (int t = 0; t < Tn; ++t) {
        // Input projection (independent of h — fills LDS-read latency).
        float gr = brz_r, gz = brz_z, gn = bi_n;
#pragma unroll
        for (int i = 0; i < In; ++i) {
            gr = fmaf(wir[i], xc[i], gr);
            gz = fmaf(wiz[i], xc[i], gz);
            gn = fmaf(win[i], xc[i], gn);
        }

        // Prefetch next x.
        float xn_[In];
        if (t + 1 < Tn) {
            const float* xq = xp + (size_t)(t + 1) * In;
#pragma unroll
            for (int i = 0; i < In; ++i) xn_[i] = xq[i];
        } else {
#pragma unroll
            for (int i = 0; i < In; ++i) xn_[i] = 0.0f;
        }

        // h broadcast: 8x ds_read_b128 (uniform addr = broadcast, no
        // conflicts), then 96 v_dot2_f32_f16 in 6 independent chains.
        const uint4* hb4 = (const uint4*)hbuf;
        float ar0 = 0.f, ar1 = 0.f;
        float az0 = 0.f, az1 = 0.f;
        float an0 = bh_n, an1 = 0.f;  // an includes b_hh_n (goes inside r*())
#pragma unroll
        for (int q = 0; q < 8; ++q) {
            uint4 u = hb4[q];
            h2 p0 = __builtin_bit_cast(h2, u.x);
            h2 p1 = __builtin_bit_cast(h2, u.y);
            h2 p2 = __builtin_bit_cast(h2, u.z);
            h2 p3 = __builtin_bit_cast(h2, u.w);
            const int k = 4 * q;
            ar0 = dot2(wr[k + 0], p0, ar0);
            az0 = dot2(wz[k + 0], p0, az0);
            an0 = dot2(wn[k + 0], p0, an0);
            ar1 = dot2(wr[k + 1], p1, ar1);
            az1 = dot2(wz[k + 1], p1, az1);
            an1 = dot2(wn[k + 1], p1, an1);
            ar0 = dot2(wr[k + 2], p2, ar0);
            az0 = dot2(wz[k + 2], p2, az0);
            an0 = dot2(wn[k + 2], p2, an0);
            ar1 = dot2(wr[k + 3], p3, ar1);
            az1 = dot2(wz[k + 3], p3, az1);
            an1 = dot2(wn[k + 3], p3, an1);
        }
        const float ar = ar0 + ar1;
        const float az = az0 + az1;
        const float an = an0 + an1;

        // Gates (fp32). tanh via exp(2x) form — saturates correctly.
        const float r = 1.0f / (1.0f + __expf(-(gr + ar)));
        const float z = 1.0f / (1.0f + __expf(-(gz + az)));
        const float pre = gn + r * an;
        const float e = __expf(2.0f * pre);
        const float nn = 1.0f - 2.0f / (e + 1.0f);
        const float hn = z * (hold - nn) + nn;  // == (1-z)*n + z*h

        op[(size_t)t * Hn + j] = hn;  // coalesced fp32 store, fire-and-forget

        // Publish h for next step (f16). Same wave, in-order LDS pipe ->
        // next iteration's ds_read sees it; no barrier.
        hbuf[j] = __builtin_bit_cast(unsigned short, (_Float16)hn);
        hold = hn;

#pragma unroll
        for (int i = 0; i < In; ++i) xc[i] = xn_[i];
    }
}

extern "C" void kernel_launch(void* const* d_in, const int* in_sizes, int n_in,
                              void* d_out, int out_size, void* d_ws, size_t ws_size,
                              hipStream_t stream) {
    gru_kernel<<<Bn, 64, 0, stream>>>(
        (const float*)d_in[0], (const float*)d_in[1], (const float*)d_in[2],
        (const float*)d_in[3], (const float*)d_in[4], (float*)d_out);
}